// Round 16
// baseline (8737.785 us; speedup 1.0000x reference)
//
#include <hip/hip_runtime.h>
#include <stdint.h>

// WeightOnlyInt4Linear: y = X @ dequant(Q)^T ; M=8192, K=4096, N=11008, G=128.
// Round 16: overlap via occupancy. BK=32 -> LDS 64KB/block -> 2 blocks/CU.
// Independent blocks phase-shift (no shared barrier): one block's ds_read
// phase runs under the other's MFMA phase (m114 co-scheduling). Minimal
// 1-barrier tile: {stage->BUF^1 ; 12 ds_read ; lgkm0 ; 32 MFMA ; vmw0 ; bar}.
// Swizzle (64B rows): phys_slot = lg ^ ((row>>1)&3); staging inverse
// kc = ((l&3)^((l>>3)&3))*8. 128 K-tiles.

typedef __attribute__((ext_vector_type(8))) short short8;
typedef __attribute__((ext_vector_type(4))) float float4v;
typedef __attribute__((ext_vector_type(4))) int int4v;
typedef __attribute__((ext_vector_type(2))) float float2v;
typedef __attribute__((ext_vector_type(4))) unsigned short ushort4v;

static constexpr int M_ = 8192;
static constexpr int K_ = 4096;
static constexpr int N_ = 11008;

__device__ __forceinline__ unsigned short f2bf(float f) {
    union { float f; uint32_t u; } v;
    v.f = f;
    uint32_t u = v.u;
    u += 0x7fffu + ((u >> 16) & 1u);  // RNE
    return (unsigned short)(u >> 16);
}

__device__ __forceinline__ void gload16(const void* g, void* l) {
    __builtin_amdgcn_global_load_lds(
        (const __attribute__((address_space(1))) uint32_t*)g,
        (__attribute__((address_space(3))) uint32_t*)l, 16, 0, 0);
}

// ---------------- Prepass 1: X fp32 -> bf16 ----------------
__global__ __launch_bounds__(256) void cvt_x_kernel(const float* __restrict__ X,
                                                    unsigned short* __restrict__ Xb) {
    const int i = blockIdx.x * 256 + threadIdx.x;
    const float4v a = ((const float4v*)X)[2 * (size_t)i];
    const float4v b = ((const float4v*)X)[2 * (size_t)i + 1];
    short8 o;
    #pragma unroll
    for (int j = 0; j < 4; ++j) o[j] = (short)f2bf(a[j]);
    #pragma unroll
    for (int j = 0; j < 4; ++j) o[4 + j] = (short)f2bf(b[j]);
    ((short8*)Xb)[(size_t)i] = o;
}

// ---------------- Prepass 2: W int4 codes -> bf16 (row-major) ----------------
__global__ __launch_bounds__(256) void deq_w_kernel(const int* __restrict__ Q,
                                                    const float* __restrict__ SZ,
                                                    unsigned short* __restrict__ Wb) {
    const int i = blockIdx.x * 256 + threadIdx.x;  // < N*K/8
    const int n = i >> 9;
    const int c = i & 511;
    const int k0 = c * 8;
    const int g = k0 >> 7;
    const float2v sz = *(const float2v*)(SZ + ((size_t)g * N_ + n) * 2);
    const float s = sz[0], z = sz[1];
    const int4v q0 = *(const int4v*)(Q + (size_t)n * K_ + k0);
    const int4v q1 = *(const int4v*)(Q + (size_t)n * K_ + k0 + 4);
    short8 o;
    #pragma unroll
    for (int j = 0; j < 4; ++j) o[j] = (short)f2bf((float)(q0[j] - 8) * s + z);
    #pragma unroll
    for (int j = 0; j < 4; ++j) o[4 + j] = (short)f2bf((float)(q1[j] - 8) * s + z);
    ((short8*)Wb)[(size_t)i] = o;
}

// ---------------- 256x256 GEMM, BK=32, 2 blocks/CU ----------------
// LDS (bytes): A buf0 [0,16K) A buf1 [16K,32K) B buf0 [32K,48K) B buf1 [48K,64K)
// Tile: 256 rows x 32 bf16 (64 B/row). phys 16B-slot = lg ^ ((row>>1)&3).

#define SBAR() __builtin_amdgcn_sched_barrier(0)
#define VMW0() asm volatile("s_waitcnt vmcnt(0)" ::: "memory")
#define LGKM0() asm volatile("s_waitcnt lgkmcnt(0)" ::: "memory")
#define BARRIER() __builtin_amdgcn_s_barrier()

__global__ __launch_bounds__(512, 4) void gemm_bf16_2cu(
    const unsigned short* __restrict__ Agl,  // [M][K] bf16
    const unsigned short* __restrict__ Bgl,  // [N][K] bf16
    float* __restrict__ C) {
    __shared__ alignas(16) unsigned short lds[32768];  // 64 KiB

    const int tid = threadIdx.x;
    const int lane = tid & 63;
    const int wid = tid >> 6;   // 0..7
    const int wr = wid >> 2;    // 0..1 -> rows wr*128..+127
    const int wc = wid & 3;     // 0..3 -> cols wc*64..+63

    // T1: XCD swizzle over 1376 = 8*172 blocks.
    const int bid = blockIdx.x;
    const int wg = (bid & 7) * 172 + (bid >> 3);
    const int mt = wg / 43;
    const int nt = wg % 43;
    const int row0 = mt * 256;
    const int col0 = nt * 256;

    // staging lane geometry: gload16 covers 16 rows x 64 B; lane row = l>>2,
    // phys chunk = l&3 -> global chunk (l&3) ^ ((row>>1)&3) = (l&3)^((l>>3)&3).
    const int srow = lane >> 2;
    const int kc = ((lane & 3) ^ ((lane >> 3) & 3)) * 8;  // k-elem offset

    // read lane geometry: row = base + l15; logical slot = lg (k = lg*8+j).
    const int l15 = lane & 15;
    const int lg = lane >> 4;
    const int pslot = (lg ^ ((l15 >> 1) & 3)) << 4;        // swizzled byte slot
    const int aB = (wr * 128 + l15) * 64 + pslot;          // + mf*1024 + BUF*16384
    const int bB = 32768 + (wc * 64 + l15) * 64 + pslot;   // + nf*1024 + BUF*16384

    const char* ldsB = (const char*)lds;
    unsigned short* ldsU = lds;
    const char* AglB = (const char*)Agl;
    const char* BglB = (const char*)Bgl;

    // Staging streams (byte offsets, +64 B per K-tile).
    uint32_t sa0 = (uint32_t)(row0 + wid * 32 + 0 + srow) * (K_ * 2) + (uint32_t)kc * 2;
    uint32_t sa1 = (uint32_t)(row0 + wid * 32 + 16 + srow) * (K_ * 2) + (uint32_t)kc * 2;
    uint32_t sb0 = (uint32_t)(col0 + wid * 32 + 0 + srow) * (K_ * 2) + (uint32_t)kc * 2;
    uint32_t sb1 = (uint32_t)(col0 + wid * 32 + 16 + srow) * (K_ * 2) + (uint32_t)kc * 2;

    auto stage = [&](int b) {  // 4 gload16/wave: A rows wid*32..+31, B same
        gload16(AglB + sa0, ldsU + b * 8192 + (wid * 32 + 0) * 32);          sa0 += 64;
        gload16(AglB + sa1, ldsU + b * 8192 + (wid * 32 + 16) * 32);         sa1 += 64;
        gload16(BglB + sb0, ldsU + 16384 + b * 8192 + (wid * 32 + 0) * 32);  sb0 += 64;
        gload16(BglB + sb1, ldsU + 16384 + b * 8192 + (wid * 32 + 16) * 32); sb1 += 64;
    };

    float4v acc[8][4] = {};

    // Prologue: stage tile 0 -> buf0; drain; barrier.
    stage(0);
    VMW0();
    BARRIER(); SBAR();

    // Per tile t (BUF=t&1): stage t+1 -> BUF^1 (no hazard: other buffer);
    // 12 ds_read from BUF; lgkm0; 32 MFMA; vmw0 (drain this tile's stages,
    // issued ~full tile earlier); barrier (tile t+1's data visible; also
    // guarantees this tile's reads of BUF precede t+2's writes into BUF).
#define KTILE(BUF, DN)                                                        \
    {                                                                         \
        if (DN) stage((BUF) ^ 1);                                             \
        short8 af[8], bf[4];                                                  \
        _Pragma("unroll")                                                     \
        for (int mf = 0; mf < 8; ++mf)                                        \
            af[mf] = *(const short8*)(ldsB + (BUF) * 16384 + mf * 1024 + aB); \
        _Pragma("unroll")                                                     \
        for (int nf = 0; nf < 4; ++nf)                                        \
            bf[nf] = *(const short8*)(ldsB + (BUF) * 16384 + nf * 1024 + bB); \
        LGKM0(); SBAR();                                                      \
        __builtin_amdgcn_s_setprio(1);                                        \
        _Pragma("unroll")                                                     \
        for (int mf = 0; mf < 8; ++mf)                                        \
            _Pragma("unroll")                                                 \
            for (int nf = 0; nf < 4; ++nf)                                    \
                acc[mf][nf] = __builtin_amdgcn_mfma_f32_16x16x32_bf16(        \
                    af[mf], bf[nf], acc[mf][nf], 0, 0, 0);                    \
        __builtin_amdgcn_s_setprio(0);                                        \
        if (DN) {                                                             \
            VMW0();                                                           \
            BARRIER(); SBAR();                                                \
        }                                                                     \
    }

    for (int t2 = 0; t2 < 126; t2 += 2) {  // tiles 0..125
        KTILE(0, 1);
        KTILE(1, 1);
    }
    KTILE(0, 1);  // tile 126: stages tile 127 -> buf1
    KTILE(1, 0);  // tile 127: pure compute
#undef KTILE

    // Epilogue: D map col=lane&15, row=(lane>>4)*4+j (m89-verified).
    const int lrow = lg * 4;
    #pragma unroll
    for (int mf = 0; mf < 8; ++mf)
        #pragma unroll
        for (int nf = 0; nf < 4; ++nf)
            #pragma unroll
            for (int j = 0; j < 4; ++j) {
                const int r = row0 + wr * 128 + mf * 16 + lrow + j;
                const int c = col0 + wc * 64 + nf * 16 + l15;
                C[(size_t)r * N_ + c] = acc[mf][nf][j];
            }
}

// ---------------- Fallback: round-1 fused kernel ----------------
static constexpr int LDSS = 40;

__global__ __launch_bounds__(256, 2) void w4_gemm_fused(
    const float* __restrict__ X, const int* __restrict__ Q,
    const float* __restrict__ SZ, float* __restrict__ C) {
    __shared__ alignas(16) unsigned short As[128 * LDSS];
    __shared__ alignas(16) unsigned short Ws[128 * LDSS];
    const int tid = threadIdx.x;
    const int lane = tid & 63;
    const int wid = tid >> 6;
    const int wrr = wid >> 1;
    const int wcc = wid & 1;
    const int row0 = blockIdx.x * 128;
    const int col0 = blockIdx.y * 128;
    float4v acc[4][4] = {};
    float4v a_reg[4];
    int4v q_reg[4];
    float2v sz_reg[4];

    auto load_tile = [&](int kb) {
        const int g = kb >> 7;
        #pragma unroll
        for (int i = 0; i < 4; ++i) {
            const int idx = tid + 256 * i;
            const int r = idx >> 3;
            const int v = idx & 7;
            a_reg[i] = *(const float4v*)(X + (size_t)(row0 + r) * K_ + kb + v * 4);
            q_reg[i] = *(const int4v*)(Q + (size_t)(col0 + r) * K_ + kb + v * 4);
            sz_reg[i] = *(const float2v*)(SZ + ((size_t)g * N_ + (col0 + r)) * 2);
        }
    };
    auto write_tile = [&]() {
        #pragma unroll
        for (int i = 0; i < 4; ++i) {
            const int idx = tid + 256 * i;
            const int r = idx >> 3;
            const int v = idx & 7;
            ushort4v ab, wb;
            #pragma unroll
            for (int j = 0; j < 4; ++j) ab[j] = f2bf(a_reg[i][j]);
            const float s = sz_reg[i][0];
            const float z = sz_reg[i][1];
            #pragma unroll
            for (int j = 0; j < 4; ++j) wb[j] = f2bf((float)(q_reg[i][j] - 8) * s + z);
            *(ushort4v*)(&As[r * LDSS + v * 4]) = ab;
            *(ushort4v*)(&Ws[r * LDSS + v * 4]) = wb;
        }
    };
    auto compute = [&]() {
        const int lr = lane & 15;
        const int lgg = lane >> 4;
        short8 af[4], bf[4];
        #pragma unroll
        for (int mf = 0; mf < 4; ++mf)
            af[mf] = *(const short8*)(&As[(wrr * 64 + mf * 16 + lr) * LDSS + lgg * 8]);
        #pragma unroll
        for (int nf = 0; nf < 4; ++nf)
            bf[nf] = *(const short8*)(&Ws[(wcc * 64 + nf * 16 + lr) * LDSS + lgg * 8]);
        #pragma unroll
        for (int mf = 0; mf < 4; ++mf)
            #pragma unroll
            for (int nf = 0; nf < 4; ++nf)
                acc[mf][nf] = __builtin_amdgcn_mfma_f32_16x16x32_bf16(
                    af[mf], bf[nf], acc[mf][nf], 0, 0, 0);
    };

    load_tile(0);
    for (int kb = 0; kb < K_; kb += 32) {
        __syncthreads();
        write_tile();
        __syncthreads();
        if (kb + 32 < K_) load_tile(kb + 32);
        compute();
    }
    const int lr = lane & 15;
    const int lgg = lane >> 4;
    #pragma unroll
    for (int mf = 0; mf < 4; ++mf)
        #pragma unroll
        for (int nf = 0; nf < 4; ++nf)
            #pragma unroll
            for (int j = 0; j < 4; ++j) {
                const int r = row0 + wrr * 64 + mf * 16 + lgg * 4 + j;
                const int c = col0 + wcc * 64 + nf * 16 + lr;
                C[(size_t)r * N_ + c] = acc[mf][nf][j];
            }
}

extern "C" void kernel_launch(void* const* d_in, const int* in_sizes, int n_in,
                              void* d_out, int out_size, void* d_ws, size_t ws_size,
                              hipStream_t stream) {
    const float* X  = (const float*)d_in[0];
    const int*   Q  = (const int*)d_in[1];
    const float* SZ = (const float*)d_in[2];
    float* C = (float*)d_out;

    const size_t xb_bytes = (size_t)M_ * K_ * 2;
    const size_t wb_bytes = (size_t)N_ * K_ * 2;
    if (ws_size >= xb_bytes + wb_bytes) {
        unsigned short* Xb = (unsigned short*)d_ws;
        unsigned short* Wb = (unsigned short*)((char*)d_ws + xb_bytes);
        cvt_x_kernel<<<(M_ * (K_ / 8)) / 256, 256, 0, stream>>>(X, Xb);
        deq_w_kernel<<<(N_ * (K_ / 8)) / 256, 256, 0, stream>>>(Q, SZ, Wb);
        gemm_bf16_2cu<<<dim3(1376), dim3(512), 0, stream>>>(Xb, Wb, C);
    } else {
        dim3 grid(M_ / 128, N_ / 128);
        w4_gemm_fused<<<grid, dim3(256), 0, stream>>>(X, Q, SZ, C);
    }
}

// Round 17
// 867.052 us; speedup vs baseline: 10.0776x; 10.0776x over previous
//
#include <hip/hip_runtime.h>
#include <stdint.h>

// WeightOnlyInt4Linear: y = X @ dequant(Q)^T ; M=8192, K=4096, N=11008, G=128.
// Round 17: 2 blocks/CU occupancy overlap, register-budgeted. Block tile
// 256x128, 8 waves (4Mx2N), 64x64 out/wave -> acc=64 VGPR, total ~116 < 128
// (2-block VGPR cap). LDS 48KB/block (BK=32 dbuf) -> 96KB/CU. Minimal
// 1-barrier K-tile: {stage 3 gloads->BUF^1 ; 8 ds_read ; lgkm0 ; 16 MFMA ;
// vmw0 ; bar}. Swizzle (64B rows, r16-proven): pslot = lg ^ ((l15>>1)&3),
// staging inverse kc = ((l&3)^((l>>3)&3))*8. 128 K-tiles. Grid 32x86=2752.

typedef __attribute__((ext_vector_type(8))) short short8;
typedef __attribute__((ext_vector_type(4))) float float4v;
typedef __attribute__((ext_vector_type(4))) int int4v;
typedef __attribute__((ext_vector_type(2))) float float2v;
typedef __attribute__((ext_vector_type(4))) unsigned short ushort4v;

static constexpr int M_ = 8192;
static constexpr int K_ = 4096;
static constexpr int N_ = 11008;

__device__ __forceinline__ unsigned short f2bf(float f) {
    union { float f; uint32_t u; } v;
    v.f = f;
    uint32_t u = v.u;
    u += 0x7fffu + ((u >> 16) & 1u);  // RNE
    return (unsigned short)(u >> 16);
}

__device__ __forceinline__ void gload16(const void* g, void* l) {
    __builtin_amdgcn_global_load_lds(
        (const __attribute__((address_space(1))) uint32_t*)g,
        (__attribute__((address_space(3))) uint32_t*)l, 16, 0, 0);
}

// ---------------- Prepass 1: X fp32 -> bf16 ----------------
__global__ __launch_bounds__(256) void cvt_x_kernel(const float* __restrict__ X,
                                                    unsigned short* __restrict__ Xb) {
    const int i = blockIdx.x * 256 + threadIdx.x;
    const float4v a = ((const float4v*)X)[2 * (size_t)i];
    const float4v b = ((const float4v*)X)[2 * (size_t)i + 1];
    short8 o;
    #pragma unroll
    for (int j = 0; j < 4; ++j) o[j] = (short)f2bf(a[j]);
    #pragma unroll
    for (int j = 0; j < 4; ++j) o[4 + j] = (short)f2bf(b[j]);
    ((short8*)Xb)[(size_t)i] = o;
}

// ---------------- Prepass 2: W int4 codes -> bf16 (row-major) ----------------
__global__ __launch_bounds__(256) void deq_w_kernel(const int* __restrict__ Q,
                                                    const float* __restrict__ SZ,
                                                    unsigned short* __restrict__ Wb) {
    const int i = blockIdx.x * 256 + threadIdx.x;  // < N*K/8
    const int n = i >> 9;
    const int c = i & 511;
    const int k0 = c * 8;
    const int g = k0 >> 7;
    const float2v sz = *(const float2v*)(SZ + ((size_t)g * N_ + n) * 2);
    const float s = sz[0], z = sz[1];
    const int4v q0 = *(const int4v*)(Q + (size_t)n * K_ + k0);
    const int4v q1 = *(const int4v*)(Q + (size_t)n * K_ + k0 + 4);
    short8 o;
    #pragma unroll
    for (int j = 0; j < 4; ++j) o[j] = (short)f2bf((float)(q0[j] - 8) * s + z);
    #pragma unroll
    for (int j = 0; j < 4; ++j) o[4 + j] = (short)f2bf((float)(q1[j] - 8) * s + z);
    ((short8*)Wb)[(size_t)i] = o;
}

// ---------------- 256x128 GEMM, BK=32, 2 blocks/CU ----------------
// LDS (bytes): A buf0 [0,16K) A buf1 [16K,32K) B buf0 [32K,40K) B buf1 [40K,48K)
// Rows of 64 B (32 bf16). phys 16B-slot = lg ^ ((row>>1)&3).

#define SBAR() __builtin_amdgcn_sched_barrier(0)
#define VMW0() asm volatile("s_waitcnt vmcnt(0)" ::: "memory")
#define LGKM0() asm volatile("s_waitcnt lgkmcnt(0)" ::: "memory")
#define BARRIER() __builtin_amdgcn_s_barrier()

__global__ __launch_bounds__(512, 4) void gemm_bf16_2cu(
    const unsigned short* __restrict__ Agl,  // [M][K] bf16
    const unsigned short* __restrict__ Bgl,  // [N][K] bf16
    float* __restrict__ C) {
    __shared__ alignas(16) unsigned short lds[24576];  // 48 KiB

    const int tid = threadIdx.x;
    const int lane = tid & 63;
    const int wid = tid >> 6;   // 0..7
    const int wr = wid >> 1;    // 0..3 -> rows wr*64..+63
    const int wc = wid & 1;     // 0..1 -> cols wc*64..+63

    // T1: XCD swizzle over 2752 = 8*344 blocks.
    const int bid = blockIdx.x;
    const int wg = (bid & 7) * 344 + (bid >> 3);
    const int mt = wg / 86;     // 0..31
    const int nt = wg % 86;     // 0..85
    const int row0 = mt * 256;
    const int col0 = nt * 128;

    // staging lane geometry: gload16 covers 16 rows x 64 B; lane row = l>>2,
    // global chunk = (l&3) ^ ((l>>3)&3).
    const int srow = lane >> 2;
    const int kc = ((lane & 3) ^ ((lane >> 3) & 3)) * 8;  // k-elem offset

    // read lane geometry: row = base + l15; logical slot = lg (k = lg*8+j).
    const int l15 = lane & 15;
    const int lg = lane >> 4;
    const int pslot = (lg ^ ((l15 >> 1) & 3)) << 4;        // swizzled byte slot
    const int aB = (wr * 64 + l15) * 64 + pslot;           // + mf*1024 + BUF*16384
    const int bB = 32768 + (wc * 64 + l15) * 64 + pslot;   // + nf*1024 + BUF*8192

    const char* ldsB = (const char*)lds;
    unsigned short* ldsU = lds;
    const char* AglB = (const char*)Agl;
    const char* BglB = (const char*)Bgl;

    // Staging streams (byte offsets, +64 B per K-tile). 3 gloads/wave/tile.
    uint32_t sa0 = (uint32_t)(row0 + wid * 32 + 0 + srow) * (K_ * 2) + (uint32_t)kc * 2;
    uint32_t sa1 = (uint32_t)(row0 + wid * 32 + 16 + srow) * (K_ * 2) + (uint32_t)kc * 2;
    uint32_t sb0 = (uint32_t)(col0 + wid * 16 + srow) * (K_ * 2) + (uint32_t)kc * 2;

    auto stage = [&](int b) {
        gload16(AglB + sa0, ldsU + b * 8192 + (wid * 32 + 0) * 32);          sa0 += 64;
        gload16(AglB + sa1, ldsU + b * 8192 + (wid * 32 + 16) * 32);         sa1 += 64;
        gload16(BglB + sb0, ldsU + 16384 + b * 4096 + (wid * 16) * 32);      sb0 += 64;
    };

    float4v acc[4][4] = {};  // 64 VGPRs

    // Prologue: stage tile 0 -> buf0; drain; barrier.
    stage(0);
    VMW0();
    BARRIER(); SBAR();

    // Per tile t (BUF=t&1): stage t+1 -> BUF^1; 8 ds_read from BUF; lgkm0;
    // 16 MFMA; vmw0; barrier.
#define KTILE(BUF, DN)                                                        \
    {                                                                         \
        if (DN) stage((BUF) ^ 1);                                             \
        short8 af[4], bf[4];                                                  \
        _Pragma("unroll")                                                     \
        for (int mf = 0; mf < 4; ++mf)                                        \
            af[mf] = *(const short8*)(ldsB + (BUF) * 16384 + mf * 1024 + aB); \
        _Pragma("unroll")                                                     \
        for (int nf = 0; nf < 4; ++nf)                                        \
            bf[nf] = *(const short8*)(ldsB + (BUF) * 8192 + nf * 1024 + bB);  \
        LGKM0(); SBAR();                                                      \
        __builtin_amdgcn_s_setprio(1);                                        \
        _Pragma("unroll")                                                     \
        for (int mf = 0; mf < 4; ++mf)                                        \
            _Pragma("unroll")                                                 \
            for (int nf = 0; nf < 4; ++nf)                                    \
                acc[mf][nf] = __builtin_amdgcn_mfma_f32_16x16x32_bf16(        \
                    af[mf], bf[nf], acc[mf][nf], 0, 0, 0);                    \
        __builtin_amdgcn_s_setprio(0);                                        \
        if (DN) {                                                             \
            VMW0();                                                           \
            BARRIER(); SBAR();                                                \
        }                                                                     \
    }

    for (int t2 = 0; t2 < 126; t2 += 2) {  // tiles 0..125
        KTILE(0, 1);
        KTILE(1, 1);
    }
    KTILE(0, 1);  // tile 126: stages tile 127 -> buf1
    KTILE(1, 0);  // tile 127: pure compute
#undef KTILE

    // Epilogue: D map col=lane&15, row=(lane>>4)*4+j (m89-verified).
    const int lrow = lg * 4;
    #pragma unroll
    for (int mf = 0; mf < 4; ++mf)
        #pragma unroll
        for (int nf = 0; nf < 4; ++nf)
            #pragma unroll
            for (int j = 0; j < 4; ++j) {
                const int r = row0 + wr * 64 + mf * 16 + lrow + j;
                const int c = col0 + wc * 64 + nf * 16 + l15;
                C[(size_t)r * N_ + c] = acc[mf][nf][j];
            }
}

// ---------------- Fallback: round-1 fused kernel ----------------
static constexpr int LDSS = 40;

__global__ __launch_bounds__(256, 2) void w4_gemm_fused(
    const float* __restrict__ X, const int* __restrict__ Q,
    const float* __restrict__ SZ, float* __restrict__ C) {
    __shared__ alignas(16) unsigned short As[128 * LDSS];
    __shared__ alignas(16) unsigned short Ws[128 * LDSS];
    const int tid = threadIdx.x;
    const int lane = tid & 63;
    const int wid = tid >> 6;
    const int wrr = wid >> 1;
    const int wcc = wid & 1;
    const int row0 = blockIdx.x * 128;
    const int col0 = blockIdx.y * 128;
    float4v acc[4][4] = {};
    float4v a_reg[4];
    int4v q_reg[4];
    float2v sz_reg[4];

    auto load_tile = [&](int kb) {
        const int g = kb >> 7;
        #pragma unroll
        for (int i = 0; i < 4; ++i) {
            const int idx = tid + 256 * i;
            const int r = idx >> 3;
            const int v = idx & 7;
            a_reg[i] = *(const float4v*)(X + (size_t)(row0 + r) * K_ + kb + v * 4);
            q_reg[i] = *(const int4v*)(Q + (size_t)(col0 + r) * K_ + kb + v * 4);
            sz_reg[i] = *(const float2v*)(SZ + ((size_t)g * N_ + (col0 + r)) * 2);
        }
    };
    auto write_tile = [&]() {
        #pragma unroll
        for (int i = 0; i < 4; ++i) {
            const int idx = tid + 256 * i;
            const int r = idx >> 3;
            const int v = idx & 7;
            ushort4v ab, wb;
            #pragma unroll
            for (int j = 0; j < 4; ++j) ab[j] = f2bf(a_reg[i][j]);
            const float s = sz_reg[i][0];
            const float z = sz_reg[i][1];
            #pragma unroll
            for (int j = 0; j < 4; ++j) wb[j] = f2bf((float)(q_reg[i][j] - 8) * s + z);
            *(ushort4v*)(&As[r * LDSS + v * 4]) = ab;
            *(ushort4v*)(&Ws[r * LDSS + v * 4]) = wb;
        }
    };
    auto compute = [&]() {
        const int lr = lane & 15;
        const int lgg = lane >> 4;
        short8 af[4], bf[4];
        #pragma unroll
        for (int mf = 0; mf < 4; ++mf)
            af[mf] = *(const short8*)(&As[(wrr * 64 + mf * 16 + lr) * LDSS + lgg * 8]);
        #pragma unroll
        for (int nf = 0; nf < 4; ++nf)
            bf[nf] = *(const short8*)(&Ws[(wcc * 64 + nf * 16 + lr) * LDSS + lgg * 8]);
        #pragma unroll
        for (int mf = 0; mf < 4; ++mf)
            #pragma unroll
            for (int nf = 0; nf < 4; ++nf)
                acc[mf][nf] = __builtin_amdgcn_mfma_f32_16x16x32_bf16(
                    af[mf], bf[nf], acc[mf][nf], 0, 0, 0);
    };

    load_tile(0);
    for (int kb = 0; kb < K_; kb += 32) {
        __syncthreads();
        write_tile();
        __syncthreads();
        if (kb + 32 < K_) load_tile(kb + 32);
        compute();
    }
    const int lr = lane & 15;
    const int lgg = lane >> 4;
    #pragma unroll
    for (int mf = 0; mf < 4; ++mf)
        #pragma unroll
        for (int nf = 0; nf < 4; ++nf)
            #pragma unroll
            for (int j = 0; j < 4; ++j) {
                const int r = row0 + wrr * 64 + mf * 16 + lgg * 4 + j;
                const int c = col0 + wcc * 64 + nf * 16 + lr;
                C[(size_t)r * N_ + c] = acc[mf][nf][j];
            }
}

extern "C" void kernel_launch(void* const* d_in, const int* in_sizes, int n_in,
                              void* d_out, int out_size, void* d_ws, size_t ws_size,
                              hipStream_t stream) {
    const float* X  = (const float*)d_in[0];
    const int*   Q  = (const int*)d_in[1];
    const float* SZ = (const float*)d_in[2];
    float* C = (float*)d_out;

    const size_t xb_bytes = (size_t)M_ * K_ * 2;
    const size_t wb_bytes = (size_t)N_ * K_ * 2;
    if (ws_size >= xb_bytes + wb_bytes) {
        unsigned short* Xb = (unsigned short*)d_ws;
        unsigned short* Wb = (unsigned short*)((char*)d_ws + xb_bytes);
        cvt_x_kernel<<<(M_ * (K_ / 8)) / 256, 256, 0, stream>>>(X, Xb);
        deq_w_kernel<<<(N_ * (K_ / 8)) / 256, 256, 0, stream>>>(Q, SZ, Wb);
        gemm_bf16_2cu<<<dim3(2752), dim3(512), 0, stream>>>(Xb, Wb, C);
    } else {
        dim3 grid(M_ / 128, N_ / 128);
        w4_gemm_fused<<<grid, dim3(256), 0, stream>>>(X, Q, SZ, C);
    }
}